// Round 1
// baseline (2997.664 us; speedup 1.0000x reference)
//
#include <hip/hip_runtime.h>
#include <hip/hip_bf16.h>
#include <cstddef>

#define BATCH 4
#define CH 256
#define HH 96
#define WW 96
#define HWN (HH*WW)               // 9216
#define NTOT (BATCH*CH*HWN)       // 9437184

// ---------------------------------------------------------------------------
// Kernel 1: all the small MLPs.
// Produces per-(b,c): warp params {cos*sc, sin*sc, tx, ty} and AdaIN
// gamma/beta for both layers.
// ---------------------------------------------------------------------------
__global__ __launch_bounds__(256) void params_kernel(
    const float* __restrict__ para, const float* __restrict__ style,
    const float* __restrict__ cw,  const float* __restrict__ cb,
    const float* __restrict__ sw,  const float* __restrict__ sb,
    const float* __restrict__ rw,  const float* __restrict__ rb,
    const float* __restrict__ tw,  const float* __restrict__ tb,
    const float* __restrict__ a1w, const float* __restrict__ a1b,
    const float* __restrict__ g1w, const float* __restrict__ g1b,
    const float* __restrict__ b1w, const float* __restrict__ b1b,
    const float* __restrict__ a2w, const float* __restrict__ a2b,
    const float* __restrict__ g2w, const float* __restrict__ g2b,
    const float* __restrict__ b2w, const float* __restrict__ b2b,
    float* __restrict__ warp, float* __restrict__ gb1, float* __restrict__ gb2)
{
  __shared__ float s_para[256], s_sty[256], s_pc[256], s_a1[128], s_a2[128];
  int b = blockIdx.x;
  int t = threadIdx.x;
  s_para[t] = para[b*256 + t];
  s_sty[t]  = style[b*256 + t];
  __syncthreads();

  // pc = relu(para @ cw + cb)
  float acc = cb[t];
  for (int i = 0; i < 256; i++) acc = fmaf(s_para[i], cw[i*256 + t], acc);
  s_pc[t] = fmaxf(acc, 0.f);

  // a1/a2 = relu(style @ aXw + aXb)   (128 outputs each)
  if (t < 128) {
    float a = a1b[t];
    for (int i = 0; i < 256; i++) a = fmaf(s_sty[i], a1w[i*128 + t], a);
    s_a1[t] = fmaxf(a, 0.f);
  } else {
    int u = t - 128;
    float a = a2b[u];
    for (int i = 0; i < 256; i++) a = fmaf(s_sty[i], a2w[i*128 + u], a);
    s_a2[u] = fmaxf(a, 0.f);
  }
  __syncthreads();

  int c = t;
  float ds = sb[c], dr = rb[c], dtx = tb[2*c], dty = tb[2*c + 1];
  for (int i = 0; i < 256; i++) {
    float p = s_pc[i];
    ds  = fmaf(p, sw[i*256 + c], ds);
    dr  = fmaf(p, rw[i*256 + c], dr);
    dtx = fmaf(p, tw[i*512 + 2*c], dtx);
    dty = fmaf(p, tw[i*512 + 2*c + 1], dty);
  }
  float scale = 2.f / (1.f + expf(-ds));
  float ang = tanhf(dr) * 3.14159f;
  float sn, cs;
  sincosf(ang, &sn, &cs);
  int bc = b*256 + c;
  warp[bc*4 + 0] = cs * scale;
  warp[bc*4 + 1] = sn * scale;
  warp[bc*4 + 2] = tanhf(dtx);
  warp[bc*4 + 3] = tanhf(dty);

  float g1 = g1b[c], be1 = b1b[c], g2 = g2b[c], be2 = b2b[c];
  for (int i = 0; i < 128; i++) {
    float a = s_a1[i];
    g1  = fmaf(a, g1w[i*256 + c], g1);
    be1 = fmaf(a, b1w[i*256 + c], be1);
  }
  for (int i = 0; i < 128; i++) {
    float a = s_a2[i];
    g2  = fmaf(a, g2w[i*256 + c], g2);
    be2 = fmaf(a, b2w[i*256 + c], be2);
  }
  gb1[bc*2] = g1; gb1[bc*2 + 1] = be1;
  gb2[bc*2] = g2; gb2[bc*2 + 1] = be2;
}

// ---------------------------------------------------------------------------
// Kernel 2: AdaAT trilinear warp, one block per (b,c) plane. Fuses the
// plane mean/var reduction and emits AdaIN-1 as per-plane scale/bias.
// ---------------------------------------------------------------------------
__global__ __launch_bounds__(256) void adaat_kernel(
    const float* __restrict__ fm, const float* __restrict__ warp,
    const float* __restrict__ gb1, float* __restrict__ tout,
    float* __restrict__ nrm1)
{
  int bc = blockIdx.x;
  int b = bc >> 8, c = bc & 255;
  float csc = warp[bc*4 + 0], ssc = warp[bc*4 + 1];
  float tx = warp[bc*4 + 2], ty = warp[bc*4 + 3];

  float gzc = 2.f * c / 255.f - 1.f;
  float iz = ((gzc + 1.f) * 256.f - 1.f) * 0.5f;
  float z0f = floorf(iz);
  float wz = iz - z0f;
  int z0 = (int)z0f;
  const float* p0 = (z0 >= 0 && z0 < 256) ? fm + (size_t)(b*256 + z0) * HWN : nullptr;
  const float* p1 = (z0 + 1 < 256) ? fm + (size_t)(b*256 + z0 + 1) * HWN : nullptr;
  float wpl0 = 1.f - wz, wpl1 = wz;

  float sum = 0.f, sumsq = 0.f;
  float* dst = tout + (size_t)bc * HWN;
  for (int idx = threadIdx.x; idx < HWN; idx += 256) {
    int h = idx / 96, w = idx - h * 96;
    float gx = 2.f * w / 95.f - 1.f;
    float gy = 2.f * h / 95.f - 1.f;
    float xw = csc * gx - ssc * gy + tx;
    float yw = ssc * gx + csc * gy + ty;
    float ix = ((xw + 1.f) * 96.f - 1.f) * 0.5f;
    float iy = ((yw + 1.f) * 96.f - 1.f) * 0.5f;
    float x0f = floorf(ix), y0f = floorf(iy);
    float wx = ix - x0f, wy = iy - y0f;
    int x0 = (int)x0f, y0 = (int)y0f;
    bool vx0 = (unsigned)x0 < 96u, vx1 = (unsigned)(x0 + 1) < 96u;
    bool vy0 = (unsigned)y0 < 96u, vy1 = (unsigned)(y0 + 1) < 96u;
    float w00 = (1.f - wy) * (1.f - wx), w01 = (1.f - wy) * wx;
    float w10 = wy * (1.f - wx),         w11 = wy * wx;
    int o00 = y0 * 96 + x0;
    float v = 0.f;
    if (p0) {
      float a00 = (vy0 && vx0) ? p0[o00]      : 0.f;
      float a01 = (vy0 && vx1) ? p0[o00 + 1]  : 0.f;
      float a10 = (vy1 && vx0) ? p0[o00 + 96] : 0.f;
      float a11 = (vy1 && vx1) ? p0[o00 + 97] : 0.f;
      v += wpl0 * (w00*a00 + w01*a01 + w10*a10 + w11*a11);
    }
    if (p1) {
      float a00 = (vy0 && vx0) ? p1[o00]      : 0.f;
      float a01 = (vy0 && vx1) ? p1[o00 + 1]  : 0.f;
      float a10 = (vy1 && vx0) ? p1[o00 + 96] : 0.f;
      float a11 = (vy1 && vx1) ? p1[o00 + 97] : 0.f;
      v += wpl1 * (w00*a00 + w01*a01 + w10*a10 + w11*a11);
    }
    dst[idx] = v;
    sum += v;
    sumsq += v * v;
  }

  // block reduction: wave shuffle + LDS
  for (int off = 32; off > 0; off >>= 1) {
    sum   += __shfl_down(sum, off, 64);
    sumsq += __shfl_down(sumsq, off, 64);
  }
  __shared__ float rs[4], rq[4];
  int lane = threadIdx.x & 63, wv = threadIdx.x >> 6;
  if (lane == 0) { rs[wv] = sum; rq[wv] = sumsq; }
  __syncthreads();
  if (threadIdx.x == 0) {
    float S = rs[0] + rs[1] + rs[2] + rs[3];
    float Q = rq[0] + rq[1] + rq[2] + rq[3];
    float m = S * (1.f / 9216.f);
    float var = Q * (1.f / 9216.f) - m * m;
    float rstd = rsqrtf(var + 1e-5f);
    float sc = (1.f + gb1[bc*2]) * rstd;
    nrm1[bc*2] = sc;
    nrm1[bc*2 + 1] = gb1[bc*2 + 1] - m * sc;
  }
}

// ---------------------------------------------------------------------------
// Kernel 3: per-plane stats of conv1 output -> AdaIN-2 scale/bias.
// ---------------------------------------------------------------------------
__global__ __launch_bounds__(256) void stats_kernel(
    const float* __restrict__ x, const float* __restrict__ gb,
    float* __restrict__ nrm)
{
  int bc = blockIdx.x;
  const float4* p = (const float4*)(x + (size_t)bc * HWN);
  float sum = 0.f, sumsq = 0.f;
  for (int i = threadIdx.x; i < HWN / 4; i += 256) {
    float4 v = p[i];
    sum   += v.x + v.y + v.z + v.w;
    sumsq += v.x*v.x + v.y*v.y + v.z*v.z + v.w*v.w;
  }
  for (int off = 32; off > 0; off >>= 1) {
    sum   += __shfl_down(sum, off, 64);
    sumsq += __shfl_down(sumsq, off, 64);
  }
  __shared__ float rs[4], rq[4];
  int lane = threadIdx.x & 63, wv = threadIdx.x >> 6;
  if (lane == 0) { rs[wv] = sum; rq[wv] = sumsq; }
  __syncthreads();
  if (threadIdx.x == 0) {
    float S = rs[0] + rs[1] + rs[2] + rs[3];
    float Q = rq[0] + rq[1] + rq[2] + rq[3];
    float m = S * (1.f / 9216.f);
    float var = Q * (1.f / 9216.f) - m * m;
    float rstd = rsqrtf(var + 1e-5f);
    float sc = (1.f + gb[bc*2]) * rstd;
    nrm[bc*2] = sc;
    nrm[bc*2 + 1] = gb[bc*2 + 1] - m * sc;
  }
}

// ---------------------------------------------------------------------------
// Kernel 4: 3x3 conv 256->256 with fused "y = lrelu(a*x + b)" on the input
// read (AdaIN + leaky relu). Output = conv + bias (raw).
// Block: 256 threads; tile 32x32 pixels x 16 c_out; thread: 2x2 px x 16 co.
// ---------------------------------------------------------------------------
__global__ __launch_bounds__(256) void conv_kernel(
    const float* __restrict__ in, const float* __restrict__ nrm,
    const float* __restrict__ cw, const float* __restrict__ cb,
    float* __restrict__ out)
{
  __shared__ float s_in[8][34][36];
  __shared__ float s_w[8][9][16];
  int b = blockIdx.z;
  int co0 = blockIdx.y * 16;
  int tile = blockIdx.x;
  int ty0 = (tile / 3) * 32, tx0 = (tile % 3) * 32;
  int t = threadIdx.x;
  int px0 = (t & 15) * 2, py0 = (t >> 4) * 2;

  float acc[4][16];
  #pragma unroll
  for (int p = 0; p < 4; p++)
    #pragma unroll
    for (int co = 0; co < 16; co++) acc[p][co] = 0.f;

  for (int ci0 = 0; ci0 < 256; ci0 += 8) {
    __syncthreads();
    // stage input tile (with halo), fusing norm + lrelu
    for (int i = t; i < 8 * 34 * 34; i += 256) {
      int ci = i / (34 * 34);
      int r = i - ci * (34 * 34);
      int ly = r / 34, lx = r - ly * 34;
      int gy = ty0 + ly - 1, gx = tx0 + lx - 1;
      float v = 0.f;
      if ((unsigned)gy < 96u && (unsigned)gx < 96u) {
        int plane = b * 256 + ci0 + ci;
        float a = nrm[plane*2], bb = nrm[plane*2 + 1];
        v = fmaf(in[(size_t)plane * HWN + gy * 96 + gx], a, bb);
        v = (v >= 0.f) ? v : 0.2f * v;
      }
      s_in[ci][ly][lx] = v;
    }
    // stage weights as [ci][tap][co] so compute reads are wave-uniform float4s
    for (int i = t; i < 8 * 144; i += 256) {
      int ci = i / 144;
      int r = i - ci * 144;
      int k = r >> 4, co = r & 15;
      s_w[ci][k][co] = cw[((size_t)(co0 + co) * 256 + (ci0 + ci)) * 9 + k];
    }
    __syncthreads();

    #pragma unroll 1
    for (int ci = 0; ci < 8; ci++) {
      float iv[4][4];
      #pragma unroll
      for (int dy = 0; dy < 4; dy++)
        #pragma unroll
        for (int dx = 0; dx < 4; dx++) iv[dy][dx] = s_in[ci][py0 + dy][px0 + dx];
      #pragma unroll
      for (int ky = 0; ky < 3; ky++)
        #pragma unroll
        for (int kx = 0; kx < 3; kx++) {
          const float* wr = &s_w[ci][ky*3 + kx][0];
          #pragma unroll
          for (int co = 0; co < 16; co++) {
            float wv = wr[co];
            acc[0][co] = fmaf(iv[ky][kx],         wv, acc[0][co]);
            acc[1][co] = fmaf(iv[ky][kx + 1],     wv, acc[1][co]);
            acc[2][co] = fmaf(iv[ky + 1][kx],     wv, acc[2][co]);
            acc[3][co] = fmaf(iv[ky + 1][kx + 1], wv, acc[3][co]);
          }
        }
    }
  }

  #pragma unroll
  for (int co = 0; co < 16; co++) {
    float bv = cb[co0 + co];
    size_t base = (size_t)(b * 256 + co0 + co) * HWN;
    int oy = ty0 + py0, ox = tx0 + px0;
    out[base + oy * 96 + ox]           = acc[0][co] + bv;
    out[base + oy * 96 + ox + 1]       = acc[1][co] + bv;
    out[base + (oy + 1) * 96 + ox]     = acc[2][co] + bv;
    out[base + (oy + 1) * 96 + ox + 1] = acc[3][co] + bv;
  }
}

// ---------------------------------------------------------------------------
extern "C" void kernel_launch(void* const* d_in, const int* in_sizes, int n_in,
                              void* d_out, int out_size, void* d_ws, size_t ws_size,
                              hipStream_t stream)
{
  const float* fm    = (const float*)d_in[0];
  const float* para  = (const float*)d_in[1];
  const float* style = (const float*)d_in[2];
  const float* cw  = (const float*)d_in[3];
  const float* cb  = (const float*)d_in[4];
  const float* sw  = (const float*)d_in[5];
  const float* sb  = (const float*)d_in[6];
  const float* rw  = (const float*)d_in[7];
  const float* rb  = (const float*)d_in[8];
  const float* tw  = (const float*)d_in[9];
  const float* tb  = (const float*)d_in[10];
  const float* a1w = (const float*)d_in[11];
  const float* a1b = (const float*)d_in[12];
  const float* g1w = (const float*)d_in[13];
  const float* g1b = (const float*)d_in[14];
  const float* b1w = (const float*)d_in[15];
  const float* b1b = (const float*)d_in[16];
  const float* c1w = (const float*)d_in[17];
  const float* c1b = (const float*)d_in[18];
  const float* a2w = (const float*)d_in[19];
  const float* a2b = (const float*)d_in[20];
  const float* g2w = (const float*)d_in[21];
  const float* g2b = (const float*)d_in[22];
  const float* b2w = (const float*)d_in[23];
  const float* b2b = (const float*)d_in[24];
  const float* c2w = (const float*)d_in[25];
  const float* c2b = (const float*)d_in[26];

  float* outf = (float*)d_out;
  float* x1   = (float*)d_ws;          // NTOT floats
  float* warp = x1 + NTOT;             // 4096
  float* gb1  = warp + 4 * 1024;       // 2048
  float* gb2  = gb1 + 2 * 1024;        // 2048
  float* nrm1 = gb2 + 2 * 1024;        // 2048
  float* nrm2 = nrm1 + 2 * 1024;       // 2048

  params_kernel<<<4, 256, 0, stream>>>(para, style, cw, cb, sw, sb, rw, rb, tw, tb,
      a1w, a1b, g1w, g1b, b1w, b1b, a2w, a2b, g2w, g2b, b2w, b2b, warp, gb1, gb2);
  // t lives in d_out (fully rewritten; consumed by conv1 before conv2 overwrites)
  adaat_kernel<<<1024, 256, 0, stream>>>(fm, warp, gb1, outf, nrm1);
  conv_kernel<<<dim3(9, 16, 4), 256, 0, stream>>>(outf, nrm1, c1w, c1b, x1);
  stats_kernel<<<1024, 256, 0, stream>>>(x1, gb2, nrm2);
  conv_kernel<<<dim3(9, 16, 4), 256, 0, stream>>>(x1, nrm2, c2w, c2b, outf);
}

// Round 2
// 315.995 us; speedup vs baseline: 9.4864x; 9.4864x over previous
//
#include <hip/hip_runtime.h>
#include <hip/hip_bf16.h>
#include <cstddef>

#define BATCH 4
#define CH 256
#define HH 96
#define WW 96
#define HWN (HH*WW)               // 9216
#define NTOT (BATCH*CH*HWN)       // 9437184
#define XT_H 98
#define XT_W 98
#define XT_PLANE (XT_H*XT_W*CH)   // per-batch elements in xt (bf16)

typedef __attribute__((ext_vector_type(16))) float f32x16;
typedef __attribute__((ext_vector_type(8))) __bf16 bfrag;
typedef __attribute__((ext_vector_type(8))) unsigned short u16x8;

static __device__ __forceinline__ unsigned short f2bf(float f) {
  unsigned int u = __float_as_uint(f);
  unsigned int r = (u + 0x7fffu + ((u >> 16) & 1u)) >> 16;
  return (unsigned short)r;
}

// ---------------------------------------------------------------------------
// Kernel 1: all the small MLPs (unchanged from R1 — passed).
// ---------------------------------------------------------------------------
__global__ __launch_bounds__(256) void params_kernel(
    const float* __restrict__ para, const float* __restrict__ style,
    const float* __restrict__ cw,  const float* __restrict__ cb,
    const float* __restrict__ sw,  const float* __restrict__ sb,
    const float* __restrict__ rw,  const float* __restrict__ rb,
    const float* __restrict__ tw,  const float* __restrict__ tb,
    const float* __restrict__ a1w, const float* __restrict__ a1b,
    const float* __restrict__ g1w, const float* __restrict__ g1b,
    const float* __restrict__ b1w, const float* __restrict__ b1b,
    const float* __restrict__ a2w, const float* __restrict__ a2b,
    const float* __restrict__ g2w, const float* __restrict__ g2b,
    const float* __restrict__ b2w, const float* __restrict__ b2b,
    float* __restrict__ warp, float* __restrict__ gb1, float* __restrict__ gb2)
{
  __shared__ float s_para[256], s_sty[256], s_pc[256], s_a1[128], s_a2[128];
  int b = blockIdx.x;
  int t = threadIdx.x;
  s_para[t] = para[b*256 + t];
  s_sty[t]  = style[b*256 + t];
  __syncthreads();

  float acc = cb[t];
  for (int i = 0; i < 256; i++) acc = fmaf(s_para[i], cw[i*256 + t], acc);
  s_pc[t] = fmaxf(acc, 0.f);

  if (t < 128) {
    float a = a1b[t];
    for (int i = 0; i < 256; i++) a = fmaf(s_sty[i], a1w[i*128 + t], a);
    s_a1[t] = fmaxf(a, 0.f);
  } else {
    int u = t - 128;
    float a = a2b[u];
    for (int i = 0; i < 256; i++) a = fmaf(s_sty[i], a2w[i*128 + u], a);
    s_a2[u] = fmaxf(a, 0.f);
  }
  __syncthreads();

  int c = t;
  float ds = sb[c], dr = rb[c], dtx = tb[2*c], dty = tb[2*c + 1];
  for (int i = 0; i < 256; i++) {
    float p = s_pc[i];
    ds  = fmaf(p, sw[i*256 + c], ds);
    dr  = fmaf(p, rw[i*256 + c], dr);
    dtx = fmaf(p, tw[i*512 + 2*c], dtx);
    dty = fmaf(p, tw[i*512 + 2*c + 1], dty);
  }
  float scale = 2.f / (1.f + expf(-ds));
  float ang = tanhf(dr) * 3.14159f;
  float sn, cs;
  sincosf(ang, &sn, &cs);
  int bc = b*256 + c;
  warp[bc*4 + 0] = cs * scale;
  warp[bc*4 + 1] = sn * scale;
  warp[bc*4 + 2] = tanhf(dtx);
  warp[bc*4 + 3] = tanhf(dty);

  float g1 = g1b[c], be1 = b1b[c], g2 = g2b[c], be2 = b2b[c];
  for (int i = 0; i < 128; i++) {
    float a = s_a1[i];
    g1  = fmaf(a, g1w[i*256 + c], g1);
    be1 = fmaf(a, b1w[i*256 + c], be1);
  }
  for (int i = 0; i < 128; i++) {
    float a = s_a2[i];
    g2  = fmaf(a, g2w[i*256 + c], g2);
    be2 = fmaf(a, b2w[i*256 + c], be2);
  }
  gb1[bc*2] = g1; gb1[bc*2 + 1] = be1;
  gb2[bc*2] = g2; gb2[bc*2 + 1] = be2;
}

// ---------------------------------------------------------------------------
// Kernel 2: weight preconversion -> wtg[tap][co][ci] bf16 (both convs).
// ---------------------------------------------------------------------------
__global__ __launch_bounds__(256) void prep_weights_kernel(
    const float* __restrict__ w1, const float* __restrict__ w2,
    unsigned short* __restrict__ wtg1, unsigned short* __restrict__ wtg2)
{
  int co = blockIdx.x & 255;
  const float* src = (blockIdx.x < 256) ? w1 : w2;
  unsigned short* dst = (blockIdx.x < 256) ? wtg1 : wtg2;
  int ci = threadIdx.x;
  const float* p = src + ((size_t)co * 256 + ci) * 9;
  #pragma unroll
  for (int tap = 0; tap < 9; tap++) {
    dst[tap * 65536 + co * 256 + ci] = f2bf(p[tap]);
  }
}

// ---------------------------------------------------------------------------
// Kernel 3: AdaAT trilinear warp + fused plane stats (unchanged from R1).
// ---------------------------------------------------------------------------
__global__ __launch_bounds__(256) void adaat_kernel(
    const float* __restrict__ fm, const float* __restrict__ warp,
    const float* __restrict__ gb1, float* __restrict__ tout,
    float* __restrict__ nrm1)
{
  int bc = blockIdx.x;
  int b = bc >> 8, c = bc & 255;
  float csc = warp[bc*4 + 0], ssc = warp[bc*4 + 1];
  float tx = warp[bc*4 + 2], ty = warp[bc*4 + 3];

  float gzc = 2.f * c / 255.f - 1.f;
  float iz = ((gzc + 1.f) * 256.f - 1.f) * 0.5f;
  float z0f = floorf(iz);
  float wz = iz - z0f;
  int z0 = (int)z0f;
  const float* p0 = (z0 >= 0 && z0 < 256) ? fm + (size_t)(b*256 + z0) * HWN : nullptr;
  const float* p1 = (z0 + 1 < 256) ? fm + (size_t)(b*256 + z0 + 1) * HWN : nullptr;
  float wpl0 = 1.f - wz, wpl1 = wz;

  float sum = 0.f, sumsq = 0.f;
  float* dst = tout + (size_t)bc * HWN;
  for (int idx = threadIdx.x; idx < HWN; idx += 256) {
    int h = idx / 96, w = idx - h * 96;
    float gx = 2.f * w / 95.f - 1.f;
    float gy = 2.f * h / 95.f - 1.f;
    float xw = csc * gx - ssc * gy + tx;
    float yw = ssc * gx + csc * gy + ty;
    float ix = ((xw + 1.f) * 96.f - 1.f) * 0.5f;
    float iy = ((yw + 1.f) * 96.f - 1.f) * 0.5f;
    float x0f = floorf(ix), y0f = floorf(iy);
    float wx = ix - x0f, wy = iy - y0f;
    int x0 = (int)x0f, y0 = (int)y0f;
    bool vx0 = (unsigned)x0 < 96u, vx1 = (unsigned)(x0 + 1) < 96u;
    bool vy0 = (unsigned)y0 < 96u, vy1 = (unsigned)(y0 + 1) < 96u;
    float w00 = (1.f - wy) * (1.f - wx), w01 = (1.f - wy) * wx;
    float w10 = wy * (1.f - wx),         w11 = wy * wx;
    int o00 = y0 * 96 + x0;
    float v = 0.f;
    if (p0) {
      float a00 = (vy0 && vx0) ? p0[o00]      : 0.f;
      float a01 = (vy0 && vx1) ? p0[o00 + 1]  : 0.f;
      float a10 = (vy1 && vx0) ? p0[o00 + 96] : 0.f;
      float a11 = (vy1 && vx1) ? p0[o00 + 97] : 0.f;
      v += wpl0 * (w00*a00 + w01*a01 + w10*a10 + w11*a11);
    }
    if (p1) {
      float a00 = (vy0 && vx0) ? p1[o00]      : 0.f;
      float a01 = (vy0 && vx1) ? p1[o00 + 1]  : 0.f;
      float a10 = (vy1 && vx0) ? p1[o00 + 96] : 0.f;
      float a11 = (vy1 && vx1) ? p1[o00 + 97] : 0.f;
      v += wpl1 * (w00*a00 + w01*a01 + w10*a10 + w11*a11);
    }
    dst[idx] = v;
    sum += v;
    sumsq += v * v;
  }

  for (int off = 32; off > 0; off >>= 1) {
    sum   += __shfl_down(sum, off, 64);
    sumsq += __shfl_down(sumsq, off, 64);
  }
  __shared__ float rs[4], rq[4];
  int lane = threadIdx.x & 63, wv = threadIdx.x >> 6;
  if (lane == 0) { rs[wv] = sum; rq[wv] = sumsq; }
  __syncthreads();
  if (threadIdx.x == 0) {
    float S = rs[0] + rs[1] + rs[2] + rs[3];
    float Q = rq[0] + rq[1] + rq[2] + rq[3];
    float m = S * (1.f / 9216.f);
    float var = Q * (1.f / 9216.f) - m * m;
    float rstd = rsqrtf(var + 1e-5f);
    float sc = (1.f + gb1[bc*2]) * rstd;
    nrm1[bc*2] = sc;
    nrm1[bc*2 + 1] = gb1[bc*2 + 1] - m * sc;
  }
}

// ---------------------------------------------------------------------------
// Kernel 4: per-plane stats (for AdaIN-2) — unchanged from R1.
// ---------------------------------------------------------------------------
__global__ __launch_bounds__(256) void stats_kernel(
    const float* __restrict__ x, const float* __restrict__ gb,
    float* __restrict__ nrm)
{
  int bc = blockIdx.x;
  const float4* p = (const float4*)(x + (size_t)bc * HWN);
  float sum = 0.f, sumsq = 0.f;
  for (int i = threadIdx.x; i < HWN / 4; i += 256) {
    float4 v = p[i];
    sum   += v.x + v.y + v.z + v.w;
    sumsq += v.x*v.x + v.y*v.y + v.z*v.z + v.w*v.w;
  }
  for (int off = 32; off > 0; off >>= 1) {
    sum   += __shfl_down(sum, off, 64);
    sumsq += __shfl_down(sumsq, off, 64);
  }
  __shared__ float rs[4], rq[4];
  int lane = threadIdx.x & 63, wv = threadIdx.x >> 6;
  if (lane == 0) { rs[wv] = sum; rq[wv] = sumsq; }
  __syncthreads();
  if (threadIdx.x == 0) {
    float S = rs[0] + rs[1] + rs[2] + rs[3];
    float Q = rq[0] + rq[1] + rq[2] + rq[3];
    float m = S * (1.f / 9216.f);
    float var = Q * (1.f / 9216.f) - m * m;
    float rstd = rsqrtf(var + 1e-5f);
    float sc = (1.f + gb[bc*2]) * rstd;
    nrm[bc*2] = sc;
    nrm[bc*2 + 1] = gb[bc*2 + 1] - m * sc;
  }
}

// ---------------------------------------------------------------------------
// Kernel 5: transpose + fused AdaIN(scale/bias) + lrelu + bf16 cvt.
// x [4][256][96][96] f32  ->  xt [4][98][98][256] bf16 with zero borders.
// One block per (hi, b); hi 0..97 <-> h = hi-1.
// ---------------------------------------------------------------------------
__global__ __launch_bounds__(256) void transpose_norm_kernel(
    const float* __restrict__ x, const float* __restrict__ nrm,
    unsigned short* __restrict__ xt)
{
  int hi = blockIdx.x;
  int b  = blockIdx.y;
  unsigned short* dst = xt + (size_t)b * XT_PLANE + (size_t)hi * (XT_W * CH);
  int t = threadIdx.x;
  int h = hi - 1;
  u16x8 zero = {0,0,0,0,0,0,0,0};
  if (h < 0 || h >= 96) {
    for (int c = t; c < XT_W * CH / 8; c += 256) ((u16x8*)dst)[c] = zero;
    return;
  }
  __shared__ unsigned short s[96 * 256];  // [w][ci]
  int ci = t;
  float sc = nrm[(b*256 + ci)*2], bi = nrm[(b*256 + ci)*2 + 1];
  const float* src = x + ((size_t)(b*256 + ci)) * HWN + h * 96;
  for (int wg = 0; wg < 24; wg++) {
    float4 v = *(const float4*)(src + wg * 4);
    float y0 = fmaf(v.x, sc, bi); y0 = (y0 >= 0.f) ? y0 : 0.2f * y0;
    float y1 = fmaf(v.y, sc, bi); y1 = (y1 >= 0.f) ? y1 : 0.2f * y1;
    float y2 = fmaf(v.z, sc, bi); y2 = (y2 >= 0.f) ? y2 : 0.2f * y2;
    float y3 = fmaf(v.w, sc, bi); y3 = (y3 >= 0.f) ? y3 : 0.2f * y3;
    s[(wg*4 + 0) * 256 + ci] = f2bf(y0);
    s[(wg*4 + 1) * 256 + ci] = f2bf(y1);
    s[(wg*4 + 2) * 256 + ci] = f2bf(y2);
    s[(wg*4 + 3) * 256 + ci] = f2bf(y3);
  }
  __syncthreads();
  // write 98 w-rows of 512B; w=0 and w=97 are zero borders
  for (int c = t; c < 98 * 32; c += 256) {
    int w = c >> 5, p = c & 31;
    u16x8 v = zero;
    if (w >= 1 && w <= 96) v = *(const u16x8*)&s[(w - 1) * 256 + p * 8];
    ((u16x8*)dst)[c] = v;
  }
}

// ---------------------------------------------------------------------------
// Kernel 6: 3x3 conv 256->256 as bf16 MFMA implicit GEMM (tap-decomposed).
// A = weights[32co x 16ci], B = patches[16ci x 32px], 9 taps accumulated.
// Block: 128 thr (2 waves). Tile: 64 co x 2 rows x 96 px. Wave: 1 row, M2xN3.
// Grid: (48 hblk, 4 coblk, 4 b) = 768 blocks = exactly 3/CU.
// ---------------------------------------------------------------------------
__global__ __launch_bounds__(128) void conv_mfma_kernel(
    const unsigned short* __restrict__ xt,   // [4][98][98][256] bf16
    const unsigned short* __restrict__ wtg,  // [9][256][256] bf16
    const float* __restrict__ cb,
    float* __restrict__ out)                 // [4][256][96][96] f32 (raw conv+bias)
{
  __shared__ __align__(16) unsigned short s_in[4 * 98 * 16]; // [row4][w98][ci16]
  __shared__ __align__(16) unsigned short s_w[9 * 64 * 16];  // [tap][co64][ci16]

  int hb  = blockIdx.x;        // h0 = hb*2
  int co0 = blockIdx.y * 64;
  int b   = blockIdx.z;
  int t = threadIdx.x, lane = t & 63, wv = t >> 6;
  int h0 = hb * 2;
  const unsigned short* xtb = xt + (size_t)b * XT_PLANE;

  f32x16 acc[2][3];
  for (int m = 0; m < 2; m++)
    for (int n = 0; n < 3; n++)
      for (int i = 0; i < 16; i++) acc[m][n][i] = 0.f;

  int l31 = lane & 31, lhi = lane >> 5;
  int aoff = l31 * 16 + lhi * 8;             // within a [co64][ci16] panel (m adds 32*16)
  int boff_lane = l31 * 16 + lhi * 8;        // within a [w98][ci16] row

  #pragma unroll 1
  for (int ks = 0; ks < 16; ks++) {
    int ci0 = ks * 16;
    __syncthreads();
    // stage input slab: rows hi=h0..h0+3, all 98 w, 16 ci  (784 x 16B chunks)
    for (int c = t; c < 784; c += 128) {
      int r = c / 196;
      int rem = c - r * 196;
      int w = rem >> 1, half = rem & 1;
      u16x8 v = *(const u16x8*)(xtb + (((h0 + r) * 98 + w) << 8) + ci0 + half * 8);
      *(u16x8*)(s_in + c * 8) = v;
    }
    // stage weights: 9 taps x 64 co x 16 ci  (1152 x 16B chunks)
    for (int c = t; c < 1152; c += 128) {
      int tap = c >> 7;
      int rem = c & 127;
      int co = rem >> 1, half = rem & 1;
      u16x8 v = *(const u16x8*)(wtg + tap * 65536 + (co0 + co) * 256 + ci0 + half * 8);
      *(u16x8*)(s_w + c * 8) = v;
    }
    __syncthreads();

    #pragma unroll
    for (int ky = 0; ky < 3; ky++) {
      const unsigned short* srow = s_in + (wv + ky) * (98 * 16);
      #pragma unroll
      for (int kx = 0; kx < 3; kx++) {
        int tap = ky * 3 + kx;
        bfrag a0 = *(const bfrag*)(s_w + tap * 1024 + aoff);
        bfrag a1 = *(const bfrag*)(s_w + tap * 1024 + 512 + aoff);
        #pragma unroll
        for (int n = 0; n < 3; n++) {
          bfrag bf = *(const bfrag*)(srow + (n * 32 + kx) * 16 + boff_lane);
          acc[0][n] = __builtin_amdgcn_mfma_f32_32x32x16_bf16(a0, bf, acc[0][n], 0, 0, 0);
          acc[1][n] = __builtin_amdgcn_mfma_f32_32x32x16_bf16(a1, bf, acc[1][n], 0, 0, 0);
        }
      }
    }
  }

  // epilogue: C[reg,lane]: col = lane&31 (px), row = (r&3)+8*(r>>2)+4*(lane>>5) (co)
  int h = h0 + wv;
  #pragma unroll
  for (int m = 0; m < 2; m++) {
    #pragma unroll
    for (int r = 0; r < 16; r++) {
      int row = (r & 3) + 8 * (r >> 2) + 4 * lhi;
      int co = co0 + m * 32 + row;
      float bv = cb[co];
      size_t base = ((size_t)(b * 256 + co) * 96 + h) * 96;
      #pragma unroll
      for (int n = 0; n < 3; n++) {
        out[base + n * 32 + l31] = acc[m][n][r] + bv;
      }
    }
  }
}

// ---------------------------------------------------------------------------
extern "C" void kernel_launch(void* const* d_in, const int* in_sizes, int n_in,
                              void* d_out, int out_size, void* d_ws, size_t ws_size,
                              hipStream_t stream)
{
  const float* fm    = (const float*)d_in[0];
  const float* para  = (const float*)d_in[1];
  const float* style = (const float*)d_in[2];
  const float* cw  = (const float*)d_in[3];
  const float* cb  = (const float*)d_in[4];
  const float* sw  = (const float*)d_in[5];
  const float* sb  = (const float*)d_in[6];
  const float* rw  = (const float*)d_in[7];
  const float* rb  = (const float*)d_in[8];
  const float* tw  = (const float*)d_in[9];
  const float* tb  = (const float*)d_in[10];
  const float* a1w = (const float*)d_in[11];
  const float* a1b = (const float*)d_in[12];
  const float* g1w = (const float*)d_in[13];
  const float* g1b = (const float*)d_in[14];
  const float* b1w = (const float*)d_in[15];
  const float* b1b = (const float*)d_in[16];
  const float* c1w = (const float*)d_in[17];
  const float* c1b = (const float*)d_in[18];
  const float* a2w = (const float*)d_in[19];
  const float* a2b = (const float*)d_in[20];
  const float* g2w = (const float*)d_in[21];
  const float* g2b = (const float*)d_in[22];
  const float* b2w = (const float*)d_in[23];
  const float* b2b = (const float*)d_in[24];
  const float* c2w = (const float*)d_in[25];
  const float* c2b = (const float*)d_in[26];

  float* outf = (float*)d_out;

  // workspace layout (bytes): xt (19,668,992) | wtg1 (1,179,648) | wtg2 | floats
  unsigned short* xtbuf = (unsigned short*)d_ws;                 // 4*98*98*256 bf16
  unsigned short* wtg1  = xtbuf + (size_t)BATCH * XT_PLANE;      // 9*256*256
  unsigned short* wtg2  = wtg1 + 9 * 256 * 256;
  float* fws  = (float*)(wtg2 + 9 * 256 * 256);
  float* warp = fws;                   // 4096
  float* gb1  = warp + 4 * 1024;       // 2048
  float* gb2  = gb1 + 2 * 1024;        // 2048
  float* nrm1 = gb2 + 2 * 1024;        // 2048
  float* nrm2 = nrm1 + 2 * 1024;       // 2048

  params_kernel<<<4, 256, 0, stream>>>(para, style, cw, cb, sw, sb, rw, rb, tw, tb,
      a1w, a1b, g1w, g1b, b1w, b1b, a2w, a2b, g2w, g2b, b2w, b2b, warp, gb1, gb2);
  prep_weights_kernel<<<512, 256, 0, stream>>>(c1w, c2w, wtg1, wtg2);
  // t lives in d_out (fp32 plane-major), fused stats -> nrm1
  adaat_kernel<<<1024, 256, 0, stream>>>(fm, warp, gb1, outf, nrm1);
  // xt1 = transpose(norm1(lrelu(t)))
  transpose_norm_kernel<<<dim3(98, 4), 256, 0, stream>>>(outf, nrm1, xtbuf);
  // y1 = conv1(xt1) -> d_out (raw conv + bias)
  conv_mfma_kernel<<<dim3(48, 4, 4), 128, 0, stream>>>(xtbuf, wtg1, c1b, outf);
  // AdaIN-2 scale/bias from y1 stats
  stats_kernel<<<1024, 256, 0, stream>>>(outf, gb2, nrm2);
  // xt2 = transpose(norm2(lrelu(y1)))  (reuses xt buffer)
  transpose_norm_kernel<<<dim3(98, 4), 256, 0, stream>>>(outf, nrm2, xtbuf);
  // final = conv2(xt2) -> d_out
  conv_mfma_kernel<<<dim3(48, 4, 4), 128, 0, stream>>>(xtbuf, wtg2, c2b, outf);
}

// Round 4
// 272.575 us; speedup vs baseline: 10.9976x; 1.1593x over previous
//
#include <hip/hip_runtime.h>
#include <hip/hip_bf16.h>
#include <cstddef>

#define BATCH 4
#define CH 256
#define HH 96
#define WW 96
#define HWN (HH*WW)               // 9216
#define NTOT (BATCH*CH*HWN)       // 9437184
#define XT_H 98
#define XT_W 98
#define XT_PLANE (XT_H*XT_W*CH)   // per-batch elements in xt (bf16)

typedef __attribute__((ext_vector_type(16))) float f32x16;
typedef __attribute__((ext_vector_type(8))) __bf16 bfrag;
typedef __attribute__((ext_vector_type(8))) unsigned short u16x8;

static __device__ __forceinline__ unsigned short f2bf(float f) {
  unsigned int u = __float_as_uint(f);
  unsigned int r = (u + 0x7fffu + ((u >> 16) & 1u)) >> 16;
  return (unsigned short)r;
}

// ---------------------------------------------------------------------------
// Kernel 1: all the small MLPs (unchanged — proven).
// ---------------------------------------------------------------------------
__global__ __launch_bounds__(256) void params_kernel(
    const float* __restrict__ para, const float* __restrict__ style,
    const float* __restrict__ cw,  const float* __restrict__ cb,
    const float* __restrict__ sw,  const float* __restrict__ sb,
    const float* __restrict__ rw,  const float* __restrict__ rb,
    const float* __restrict__ tw,  const float* __restrict__ tb,
    const float* __restrict__ a1w, const float* __restrict__ a1b,
    const float* __restrict__ g1w, const float* __restrict__ g1b,
    const float* __restrict__ b1w, const float* __restrict__ b1b,
    const float* __restrict__ a2w, const float* __restrict__ a2b,
    const float* __restrict__ g2w, const float* __restrict__ g2b,
    const float* __restrict__ b2w, const float* __restrict__ b2b,
    float* __restrict__ warp, float* __restrict__ gb1, float* __restrict__ gb2)
{
  __shared__ float s_para[256], s_sty[256], s_pc[256], s_a1[128], s_a2[128];
  int b = blockIdx.x;
  int t = threadIdx.x;
  s_para[t] = para[b*256 + t];
  s_sty[t]  = style[b*256 + t];
  __syncthreads();

  float acc = cb[t];
  for (int i = 0; i < 256; i++) acc = fmaf(s_para[i], cw[i*256 + t], acc);
  s_pc[t] = fmaxf(acc, 0.f);

  if (t < 128) {
    float a = a1b[t];
    for (int i = 0; i < 256; i++) a = fmaf(s_sty[i], a1w[i*128 + t], a);
    s_a1[t] = fmaxf(a, 0.f);
  } else {
    int u = t - 128;
    float a = a2b[u];
    for (int i = 0; i < 256; i++) a = fmaf(s_sty[i], a2w[i*128 + u], a);
    s_a2[u] = fmaxf(a, 0.f);
  }
  __syncthreads();

  int c = t;
  float ds = sb[c], dr = rb[c], dtx = tb[2*c], dty = tb[2*c + 1];
  for (int i = 0; i < 256; i++) {
    float p = s_pc[i];
    ds  = fmaf(p, sw[i*256 + c], ds);
    dr  = fmaf(p, rw[i*256 + c], dr);
    dtx = fmaf(p, tw[i*512 + 2*c], dtx);
    dty = fmaf(p, tw[i*512 + 2*c + 1], dty);
  }
  float scale = 2.f / (1.f + expf(-ds));
  float ang = tanhf(dr) * 3.14159f;
  float sn, cs;
  sincosf(ang, &sn, &cs);
  int bc = b*256 + c;
  warp[bc*4 + 0] = cs * scale;
  warp[bc*4 + 1] = sn * scale;
  warp[bc*4 + 2] = tanhf(dtx);
  warp[bc*4 + 3] = tanhf(dty);

  float g1 = g1b[c], be1 = b1b[c], g2 = g2b[c], be2 = b2b[c];
  for (int i = 0; i < 128; i++) {
    float a = s_a1[i];
    g1  = fmaf(a, g1w[i*256 + c], g1);
    be1 = fmaf(a, b1w[i*256 + c], be1);
  }
  for (int i = 0; i < 128; i++) {
    float a = s_a2[i];
    g2  = fmaf(a, g2w[i*256 + c], g2);
    be2 = fmaf(a, b2w[i*256 + c], be2);
  }
  gb1[bc*2] = g1; gb1[bc*2 + 1] = be1;
  gb2[bc*2] = g2; gb2[bc*2 + 1] = be2;
}

// ---------------------------------------------------------------------------
// Kernel 2: weight preconversion into per-lane MFMA fragment order:
// wf[coblk4][ks16][tap9][m2][lane64][8]  (A[co][ci] frag for 32x32x16 bf16)
//   co = coblk*64 + m*32 + (l&31), ci = ks*16 + (l>>5)*8 + j
// ---------------------------------------------------------------------------
__global__ __launch_bounds__(256) void prep_weights_kernel(
    const float* __restrict__ w1, const float* __restrict__ w2,
    unsigned short* __restrict__ wf1, unsigned short* __restrict__ wf2)
{
  int co = blockIdx.x & 255;
  const float* src = (blockIdx.x < 256) ? w1 : w2;
  unsigned short* dst = (blockIdx.x < 256) ? wf1 : wf2;
  int ci = threadIdx.x;
  int coblk = co >> 6, m = (co >> 5) & 1;
  int l = (co & 31) | (((ci >> 3) & 1) << 5);
  int ks = ci >> 4, j = ci & 7;
  const float* p = src + ((size_t)co * 256 + ci) * 9;
  #pragma unroll
  for (int tap = 0; tap < 9; tap++) {
    size_t idx = (((size_t)((coblk * 16 + ks) * 9 + tap) * 2 + m) * 64 + l) * 8 + j;
    dst[idx] = f2bf(p[tap]);
  }
}

// ---------------------------------------------------------------------------
// Kernel 3: AdaAT trilinear warp + fused plane stats (unchanged — proven).
// ---------------------------------------------------------------------------
__global__ __launch_bounds__(256) void adaat_kernel(
    const float* __restrict__ fm, const float* __restrict__ warp,
    const float* __restrict__ gb1, float* __restrict__ tout,
    float* __restrict__ nrm1)
{
  int bc = blockIdx.x;
  int b = bc >> 8, c = bc & 255;
  float csc = warp[bc*4 + 0], ssc = warp[bc*4 + 1];
  float tx = warp[bc*4 + 2], ty = warp[bc*4 + 3];

  float gzc = 2.f * c / 255.f - 1.f;
  float iz = ((gzc + 1.f) * 256.f - 1.f) * 0.5f;
  float z0f = floorf(iz);
  float wz = iz - z0f;
  int z0 = (int)z0f;
  const float* p0 = (z0 >= 0 && z0 < 256) ? fm + (size_t)(b*256 + z0) * HWN : nullptr;
  const float* p1 = (z0 + 1 < 256) ? fm + (size_t)(b*256 + z0 + 1) * HWN : nullptr;
  float wpl0 = 1.f - wz, wpl1 = wz;

  float sum = 0.f, sumsq = 0.f;
  float* dst = tout + (size_t)bc * HWN;
  for (int idx = threadIdx.x; idx < HWN; idx += 256) {
    int h = idx / 96, w = idx - h * 96;
    float gx = 2.f * w / 95.f - 1.f;
    float gy = 2.f * h / 95.f - 1.f;
    float xw = csc * gx - ssc * gy + tx;
    float yw = ssc * gx + csc * gy + ty;
    float ix = ((xw + 1.f) * 96.f - 1.f) * 0.5f;
    float iy = ((yw + 1.f) * 96.f - 1.f) * 0.5f;
    float x0f = floorf(ix), y0f = floorf(iy);
    float wx = ix - x0f, wy = iy - y0f;
    int x0 = (int)x0f, y0 = (int)y0f;
    bool vx0 = (unsigned)x0 < 96u, vx1 = (unsigned)(x0 + 1) < 96u;
    bool vy0 = (unsigned)y0 < 96u, vy1 = (unsigned)(y0 + 1) < 96u;
    float w00 = (1.f - wy) * (1.f - wx), w01 = (1.f - wy) * wx;
    float w10 = wy * (1.f - wx),         w11 = wy * wx;
    int o00 = y0 * 96 + x0;
    float v = 0.f;
    if (p0) {
      float a00 = (vy0 && vx0) ? p0[o00]      : 0.f;
      float a01 = (vy0 && vx1) ? p0[o00 + 1]  : 0.f;
      float a10 = (vy1 && vx0) ? p0[o00 + 96] : 0.f;
      float a11 = (vy1 && vx1) ? p0[o00 + 97] : 0.f;
      v += wpl0 * (w00*a00 + w01*a01 + w10*a10 + w11*a11);
    }
    if (p1) {
      float a00 = (vy0 && vx0) ? p1[o00]      : 0.f;
      float a01 = (vy0 && vx1) ? p1[o00 + 1]  : 0.f;
      float a10 = (vy1 && vx0) ? p1[o00 + 96] : 0.f;
      float a11 = (vy1 && vx1) ? p1[o00 + 97] : 0.f;
      v += wpl1 * (w00*a00 + w01*a01 + w10*a10 + w11*a11);
    }
    dst[idx] = v;
    sum += v;
    sumsq += v * v;
  }

  for (int off = 32; off > 0; off >>= 1) {
    sum   += __shfl_down(sum, off, 64);
    sumsq += __shfl_down(sumsq, off, 64);
  }
  __shared__ float rs[4], rq[4];
  int lane = threadIdx.x & 63, wv = threadIdx.x >> 6;
  if (lane == 0) { rs[wv] = sum; rq[wv] = sumsq; }
  __syncthreads();
  if (threadIdx.x == 0) {
    float S = rs[0] + rs[1] + rs[2] + rs[3];
    float Q = rq[0] + rq[1] + rq[2] + rq[3];
    float m = S * (1.f / 9216.f);
    float var = Q * (1.f / 9216.f) - m * m;
    float rstd = rsqrtf(var + 1e-5f);
    float sc = (1.f + gb1[bc*2]) * rstd;
    nrm1[bc*2] = sc;
    nrm1[bc*2 + 1] = gb1[bc*2 + 1] - m * sc;
  }
}

// ---------------------------------------------------------------------------
// Kernel 4: per-plane stats (for AdaIN-2) — unchanged.
// ---------------------------------------------------------------------------
__global__ __launch_bounds__(256) void stats_kernel(
    const float* __restrict__ x, const float* __restrict__ gb,
    float* __restrict__ nrm)
{
  int bc = blockIdx.x;
  const float4* p = (const float4*)(x + (size_t)bc * HWN);
  float sum = 0.f, sumsq = 0.f;
  for (int i = threadIdx.x; i < HWN / 4; i += 256) {
    float4 v = p[i];
    sum   += v.x + v.y + v.z + v.w;
    sumsq += v.x*v.x + v.y*v.y + v.z*v.z + v.w*v.w;
  }
  for (int off = 32; off > 0; off >>= 1) {
    sum   += __shfl_down(sum, off, 64);
    sumsq += __shfl_down(sumsq, off, 64);
  }
  __shared__ float rs[4], rq[4];
  int lane = threadIdx.x & 63, wv = threadIdx.x >> 6;
  if (lane == 0) { rs[wv] = sum; rq[wv] = sumsq; }
  __syncthreads();
  if (threadIdx.x == 0) {
    float S = rs[0] + rs[1] + rs[2] + rs[3];
    float Q = rq[0] + rq[1] + rq[2] + rq[3];
    float m = S * (1.f / 9216.f);
    float var = Q * (1.f / 9216.f) - m * m;
    float rstd = rsqrtf(var + 1e-5f);
    float sc = (1.f + gb[bc*2]) * rstd;
    nrm[bc*2] = sc;
    nrm[bc*2 + 1] = gb[bc*2 + 1] - m * sc;
  }
}

// ---------------------------------------------------------------------------
// Kernel 5: transpose + fused AdaIN(scale/bias) + lrelu + bf16 cvt (unchanged).
// x [4][256][96][96] f32  ->  xt [4][98][98][256] bf16 with zero borders.
// ---------------------------------------------------------------------------
__global__ __launch_bounds__(256) void transpose_norm_kernel(
    const float* __restrict__ x, const float* __restrict__ nrm,
    unsigned short* __restrict__ xt)
{
  int hi = blockIdx.x;
  int b  = blockIdx.y;
  unsigned short* dst = xt + (size_t)b * XT_PLANE + (size_t)hi * (XT_W * CH);
  int t = threadIdx.x;
  int h = hi - 1;
  u16x8 zero = {0,0,0,0,0,0,0,0};
  if (h < 0 || h >= 96) {
    for (int c = t; c < XT_W * CH / 8; c += 256) ((u16x8*)dst)[c] = zero;
    return;
  }
  __shared__ unsigned short s[96 * 256];  // [w][ci]
  int ci = t;
  float sc = nrm[(b*256 + ci)*2], bi = nrm[(b*256 + ci)*2 + 1];
  const float* src = x + ((size_t)(b*256 + ci)) * HWN + h * 96;
  for (int wg = 0; wg < 24; wg++) {
    float4 v = *(const float4*)(src + wg * 4);
    float y0 = fmaf(v.x, sc, bi); y0 = (y0 >= 0.f) ? y0 : 0.2f * y0;
    float y1 = fmaf(v.y, sc, bi); y1 = (y1 >= 0.f) ? y1 : 0.2f * y1;
    float y2 = fmaf(v.z, sc, bi); y2 = (y2 >= 0.f) ? y2 : 0.2f * y2;
    float y3 = fmaf(v.w, sc, bi); y3 = (y3 >= 0.f) ? y3 : 0.2f * y3;
    s[(wg*4 + 0) * 256 + ci] = f2bf(y0);
    s[(wg*4 + 1) * 256 + ci] = f2bf(y1);
    s[(wg*4 + 2) * 256 + ci] = f2bf(y2);
    s[(wg*4 + 3) * 256 + ci] = f2bf(y3);
  }
  __syncthreads();
  for (int c = t; c < 98 * 32; c += 256) {
    int w = c >> 5, p = c & 31;
    u16x8 v = zero;
    if (w >= 1 && w <= 96) v = *(const u16x8*)&s[(w - 1) * 256 + p * 8];
    ((u16x8*)dst)[c] = v;
  }
}

// ---------------------------------------------------------------------------
// Kernel 6: 3x3 conv 256->256, bf16 MFMA implicit GEMM, tap-decomposed.
// R3: conflict-free split-half LDS layout s_in[r4][half2][w98][8ci],
//     weights direct global->reg from frag-formatted wf, LDS double-buffer,
//     one barrier per K-step.
// Block: 128 thr (2 waves). Tile: 64 co x 2 rows x 96 px. Grid 48x4x4 = 768.
// ---------------------------------------------------------------------------
__global__ __launch_bounds__(128) void conv_mfma_kernel(
    const unsigned short* __restrict__ xt,   // [4][98][98][256] bf16
    const unsigned short* __restrict__ wf,   // frag layout (see prep)
    const float* __restrict__ cb,
    float* __restrict__ out)                 // [4][256][96][96] f32
{
  __shared__ __align__(16) unsigned short s_in[2][6272]; // [buf][r4*half2*w98*8ci]

  int hb = blockIdx.x, coblk = blockIdx.y, b = blockIdx.z;
  int co0 = coblk * 64, h0 = hb * 2;
  int t = threadIdx.x, lane = t & 63, wv = t >> 6;
  int l31 = lane & 31, lhi = lane >> 5;
  const unsigned short* xtb = xt + (size_t)b * XT_PLANE;

  // stage chunk descriptors: chunk c = ((r*2+half)*98 + w), c = t + i*128
  int pre_g[7], pre_l[7];
  #pragma unroll
  for (int i = 0; i < 7; i++) {
    int c = t + i * 128;
    if (c < 784) {
      int r = c / 196;
      int rem = c - r * 196;
      int half = rem / 98;
      int w = rem - half * 98;
      pre_g[i] = ((h0 + r) * 98 + w) * 256 + half * 8;  // element offset (+ks*16)
      pre_l[i] = c * 8;                                 // element offset in buf
    }
  }

  f32x16 acc[2][3];
  #pragma unroll
  for (int m = 0; m < 2; m++)
    #pragma unroll
    for (int n = 0; n < 3; n++)
      #pragma unroll
      for (int i = 0; i < 16; i++) acc[m][n][i] = 0.f;

  // per-lane A-frag base: wf + (coblk*16+ks)*9216 + tap*1024 + m*512 + lane*8
  const unsigned short* wfb = wf + (size_t)(coblk * 16) * 9216 + lane * 8;

  // prologue: stage ks=0 into buf 0
  u16x8 stg[7];
  #pragma unroll
  for (int i = 0; i < 6; i++) stg[i] = *(const u16x8*)(xtb + pre_g[i]);
  if (t < 16) stg[6] = *(const u16x8*)(xtb + pre_g[6]);
  #pragma unroll
  for (int i = 0; i < 6; i++) *(u16x8*)(&s_in[0][pre_l[i]]) = stg[i];
  if (t < 16) *(u16x8*)(&s_in[0][pre_l[6]]) = stg[6];
  __syncthreads();

  int buf = 0;
  int boff = (lhi * 98 + l31) * 8;
  #pragma unroll 1
  for (int ks = 0; ks < 16; ks++) {
    // A-fragments for this ks (global->reg, issued first so their vmcnt
    // waits don't drain the stage loads)
    const unsigned short* wk = wfb + (size_t)ks * 9216;
    bfrag wa[9][2];
    #pragma unroll
    for (int tap = 0; tap < 9; tap++) {
      wa[tap][0] = *(const bfrag*)(wk + tap * 1024);
      wa[tap][1] = *(const bfrag*)(wk + tap * 1024 + 512);
    }
    // early-issue next K-step's stage loads (latency hides under MFMA)
    if (ks < 15) {
      int cib = (ks + 1) * 16;
      #pragma unroll
      for (int i = 0; i < 6; i++) stg[i] = *(const u16x8*)(xtb + pre_g[i] + cib);
      if (t < 16) stg[6] = *(const u16x8*)(xtb + pre_g[6] + cib);
    }
    // compute on current buffer
    const unsigned short* sb = s_in[buf];
    #pragma unroll
    for (int ky = 0; ky < 3; ky++) {
      const unsigned short* srow = sb + (wv + ky) * (2 * 98 * 8);
      #pragma unroll
      for (int kx = 0; kx < 3; kx++) {
        int tap = ky * 3 + kx;
        #pragma unroll
        for (int n = 0; n < 3; n++) {
          bfrag bv = *(const bfrag*)(srow + (n * 32 + kx) * 8 + boff);
          acc[0][n] = __builtin_amdgcn_mfma_f32_32x32x16_bf16(wa[tap][0], bv, acc[0][n], 0, 0, 0);
          acc[1][n] = __builtin_amdgcn_mfma_f32_32x32x16_bf16(wa[tap][1], bv, acc[1][n], 0, 0, 0);
        }
      }
    }
    // write next buffer, single barrier per K-step
    if (ks < 15) {
      unsigned short* sn = s_in[buf ^ 1];
      #pragma unroll
      for (int i = 0; i < 6; i++) *(u16x8*)(&sn[pre_l[i]]) = stg[i];
      if (t < 16) *(u16x8*)(&sn[pre_l[6]]) = stg[6];
    }
    __syncthreads();
    buf ^= 1;
  }

  // epilogue: C[reg,lane]: col = lane&31 (px), row = (r&3)+8*(r>>2)+4*(lane>>5)
  int h = h0 + wv;
  #pragma unroll
  for (int m = 0; m < 2; m++) {
    #pragma unroll
    for (int r = 0; r < 16; r++) {
      int row = (r & 3) + 8 * (r >> 2) + 4 * lhi;
      int co = co0 + m * 32 + row;
      float bv = cb[co];
      size_t base = ((size_t)(b * 256 + co) * 96 + h) * 96;
      #pragma unroll
      for (int n = 0; n < 3; n++) {
        out[base + n * 32 + l31] = acc[m][n][r] + bv;
      }
    }
  }
}

// ---------------------------------------------------------------------------
extern "C" void kernel_launch(void* const* d_in, const int* in_sizes, int n_in,
                              void* d_out, int out_size, void* d_ws, size_t ws_size,
                              hipStream_t stream)
{
  const float* fm    = (const float*)d_in[0];
  const float* para  = (const float*)d_in[1];
  const float* style = (const float*)d_in[2];
  const float* cw  = (const float*)d_in[3];
  const float* cb  = (const float*)d_in[4];
  const float* sw  = (const float*)d_in[5];
  const float* sb  = (const float*)d_in[6];
  const float* rw  = (const float*)d_in[7];
  const float* rb  = (const float*)d_in[8];
  const float* tw  = (const float*)d_in[9];
  const float* tb  = (const float*)d_in[10];
  const float* a1w = (const float*)d_in[11];
  const float* a1b = (const float*)d_in[12];
  const float* g1w = (const float*)d_in[13];
  const float* g1b = (const float*)d_in[14];
  const float* b1w = (const float*)d_in[15];
  const float* b1b = (const float*)d_in[16];
  const float* c1w = (const float*)d_in[17];
  const float* c1b = (const float*)d_in[18];
  const float* a2w = (const float*)d_in[19];
  const float* a2b = (const float*)d_in[20];
  const float* g2w = (const float*)d_in[21];
  const float* g2b = (const float*)d_in[22];
  const float* b2w = (const float*)d_in[23];
  const float* b2b = (const float*)d_in[24];
  const float* c2w = (const float*)d_in[25];
  const float* c2b = (const float*)d_in[26];

  float* outf = (float*)d_out;

  unsigned short* xtbuf = (unsigned short*)d_ws;                 // 4*98*98*256 bf16
  unsigned short* wf1   = xtbuf + (size_t)BATCH * XT_PLANE;      // 589824
  unsigned short* wf2   = wf1 + 9 * 256 * 256;
  float* fws  = (float*)(wf2 + 9 * 256 * 256);
  float* warp = fws;                   // 4096
  float* gb1  = warp + 4 * 1024;       // 2048
  float* gb2  = gb1 + 2 * 1024;        // 2048
  float* nrm1 = gb2 + 2 * 1024;        // 2048
  float* nrm2 = nrm1 + 2 * 1024;       // 2048

  params_kernel<<<4, 256, 0, stream>>>(para, style, cw, cb, sw, sb, rw, rb, tw, tb,
      a1w, a1b, g1w, g1b, b1w, b1b, a2w, a2b, g2w, g2b, b2w, b2b, warp, gb1, gb2);
  prep_weights_kernel<<<512, 256, 0, stream>>>(c1w, c2w, wf1, wf2);
  adaat_kernel<<<1024, 256, 0, stream>>>(fm, warp, gb1, outf, nrm1);
  transpose_norm_kernel<<<dim3(98, 4), 256, 0, stream>>>(outf, nrm1, xtbuf);
  conv_mfma_kernel<<<dim3(48, 4, 4), 128, 0, stream>>>(xtbuf, wf1, c1b, outf);
  stats_kernel<<<1024, 256, 0, stream>>>(outf, gb2, nrm2);
  transpose_norm_kernel<<<dim3(98, 4), 256, 0, stream>>>(outf, nrm2, xtbuf);
  conv_mfma_kernel<<<dim3(48, 4, 4), 128, 0, stream>>>(xtbuf, wf2, c2b, outf);
}

// Round 5
// 263.874 us; speedup vs baseline: 11.3602x; 1.0330x over previous
//
#include <hip/hip_runtime.h>
#include <hip/hip_bf16.h>
#include <cstddef>

#define BATCH 4
#define CH 256
#define HH 96
#define WW 96
#define HWN (HH*WW)               // 9216
#define NTOT (BATCH*CH*HWN)       // 9437184
#define XT_H 98
#define XT_W 98
#define XT_PLANE (XT_H*XT_W*CH)   // per-batch elements in xt (bf16)

typedef __attribute__((ext_vector_type(16))) float f32x16;
typedef __attribute__((ext_vector_type(8))) __bf16 bfrag;
typedef __attribute__((ext_vector_type(8))) unsigned short u16x8;

static __device__ __forceinline__ unsigned short f2bf(float f) {
  unsigned int u = __float_as_uint(f);
  unsigned int r = (u + 0x7fffu + ((u >> 16) & 1u)) >> 16;
  return (unsigned short)r;
}

// ---------------------------------------------------------------------------
// Kernel 1: all the small MLPs (unchanged — proven).
// ---------------------------------------------------------------------------
__global__ __launch_bounds__(256) void params_kernel(
    const float* __restrict__ para, const float* __restrict__ style,
    const float* __restrict__ cw,  const float* __restrict__ cb,
    const float* __restrict__ sw,  const float* __restrict__ sb,
    const float* __restrict__ rw,  const float* __restrict__ rb,
    const float* __restrict__ tw,  const float* __restrict__ tb,
    const float* __restrict__ a1w, const float* __restrict__ a1b,
    const float* __restrict__ g1w, const float* __restrict__ g1b,
    const float* __restrict__ b1w, const float* __restrict__ b1b,
    const float* __restrict__ a2w, const float* __restrict__ a2b,
    const float* __restrict__ g2w, const float* __restrict__ g2b,
    const float* __restrict__ b2w, const float* __restrict__ b2b,
    float* __restrict__ warp, float* __restrict__ gb1, float* __restrict__ gb2)
{
  __shared__ float s_para[256], s_sty[256], s_pc[256], s_a1[128], s_a2[128];
  int b = blockIdx.x;
  int t = threadIdx.x;
  s_para[t] = para[b*256 + t];
  s_sty[t]  = style[b*256 + t];
  __syncthreads();

  float acc = cb[t];
  for (int i = 0; i < 256; i++) acc = fmaf(s_para[i], cw[i*256 + t], acc);
  s_pc[t] = fmaxf(acc, 0.f);

  if (t < 128) {
    float a = a1b[t];
    for (int i = 0; i < 256; i++) a = fmaf(s_sty[i], a1w[i*128 + t], a);
    s_a1[t] = fmaxf(a, 0.f);
  } else {
    int u = t - 128;
    float a = a2b[u];
    for (int i = 0; i < 256; i++) a = fmaf(s_sty[i], a2w[i*128 + u], a);
    s_a2[u] = fmaxf(a, 0.f);
  }
  __syncthreads();

  int c = t;
  float ds = sb[c], dr = rb[c], dtx = tb[2*c], dty = tb[2*c + 1];
  for (int i = 0; i < 256; i++) {
    float p = s_pc[i];
    ds  = fmaf(p, sw[i*256 + c], ds);
    dr  = fmaf(p, rw[i*256 + c], dr);
    dtx = fmaf(p, tw[i*512 + 2*c], dtx);
    dty = fmaf(p, tw[i*512 + 2*c + 1], dty);
  }
  float scale = 2.f / (1.f + expf(-ds));
  float ang = tanhf(dr) * 3.14159f;
  float sn, cs;
  sincosf(ang, &sn, &cs);
  int bc = b*256 + c;
  warp[bc*4 + 0] = cs * scale;
  warp[bc*4 + 1] = sn * scale;
  warp[bc*4 + 2] = tanhf(dtx);
  warp[bc*4 + 3] = tanhf(dty);

  float g1 = g1b[c], be1 = b1b[c], g2 = g2b[c], be2 = b2b[c];
  for (int i = 0; i < 128; i++) {
    float a = s_a1[i];
    g1  = fmaf(a, g1w[i*256 + c], g1);
    be1 = fmaf(a, b1w[i*256 + c], be1);
  }
  for (int i = 0; i < 128; i++) {
    float a = s_a2[i];
    g2  = fmaf(a, g2w[i*256 + c], g2);
    be2 = fmaf(a, b2w[i*256 + c], be2);
  }
  gb1[bc*2] = g1; gb1[bc*2 + 1] = be1;
  gb2[bc*2] = g2; gb2[bc*2 + 1] = be2;
}

// ---------------------------------------------------------------------------
// Kernel 2: weight preconversion into per-lane MFMA fragment order (proven).
// wf[coblk4][ks16][tap9][m2][lane64][8]
// ---------------------------------------------------------------------------
__global__ __launch_bounds__(256) void prep_weights_kernel(
    const float* __restrict__ w1, const float* __restrict__ w2,
    unsigned short* __restrict__ wf1, unsigned short* __restrict__ wf2)
{
  int co = blockIdx.x & 255;
  const float* src = (blockIdx.x < 256) ? w1 : w2;
  unsigned short* dst = (blockIdx.x < 256) ? wf1 : wf2;
  int ci = threadIdx.x;
  int coblk = co >> 6, m = (co >> 5) & 1;
  int l = (co & 31) | (((ci >> 3) & 1) << 5);
  int ks = ci >> 4, j = ci & 7;
  const float* p = src + ((size_t)co * 256 + ci) * 9;
  #pragma unroll
  for (int tap = 0; tap < 9; tap++) {
    size_t idx = (((size_t)((coblk * 16 + ks) * 9 + tap) * 2 + m) * 64 + l) * 8 + j;
    dst[idx] = f2bf(p[tap]);
  }
}

// ---------------------------------------------------------------------------
// Kernel 3 (R5): AdaAT trilinear warp, QUARTER-plane per block (4096 blocks),
// fully-unrolled 9 px/thread, affine incremental coords, partial stats out.
// ---------------------------------------------------------------------------
__global__ __launch_bounds__(256) void adaat_kernel(
    const float* __restrict__ fm, const float* __restrict__ warp,
    float* __restrict__ tout, float* __restrict__ part)
{
  int bid = blockIdx.x;
  int bc = bid >> 2, q = bid & 3;
  int b = bc >> 8, c = bc & 255;
  float csc = warp[bc*4 + 0], ssc = warp[bc*4 + 1];
  float tx = warp[bc*4 + 2], ty = warp[bc*4 + 3];

  // affine pixel->sample coords: ix = axw*w + axh*h + ax0 (and same for iy)
  // gx = 2w/95-1, gy = 2h/95-1; xw = csc*gx - ssc*gy + tx;
  // ix = ((xw+1)*96-1)*0.5 = 48*xw + 47.5
  const float axw = csc * (2.f / 95.f) * 48.f;
  const float axh = -ssc * (2.f / 95.f) * 48.f;
  const float ax0 = 48.f * (tx - csc + ssc) + 47.5f;
  const float ayw = ssc * (2.f / 95.f) * 48.f;
  const float ayh = csc * (2.f / 95.f) * 48.f;
  const float ay0 = 48.f * (ty - ssc - csc) + 47.5f;

  float gzc = 2.f * c / 255.f - 1.f;
  float iz = ((gzc + 1.f) * 256.f - 1.f) * 0.5f;
  float z0f = floorf(iz);
  float wz = iz - z0f;
  int z0 = (int)z0f;
  const float* p0 = (z0 >= 0 && z0 < 256) ? fm + (size_t)(b*256 + z0) * HWN : nullptr;
  const float* p1 = (z0 + 1 < 256) ? fm + (size_t)(b*256 + z0 + 1) * HWN : nullptr;
  float wpl0 = 1.f - wz, wpl1 = wz;

  int t = threadIdx.x;
  int h = q * 24 + t / 96;   // rows q*24 .. q*24+23
  int w = t % 96;
  float* dst = tout + (size_t)bc * HWN + q * 2304 + t;

  float sum = 0.f, sumsq = 0.f;
  #pragma unroll
  for (int k = 0; k < 9; k++) {
    float fw = (float)w, fh = (float)h;
    float ix = fmaf(axw, fw, fmaf(axh, fh, ax0));
    float iy = fmaf(ayw, fw, fmaf(ayh, fh, ay0));
    float x0f = floorf(ix), y0f = floorf(iy);
    float wx = ix - x0f, wy = iy - y0f;
    int x0 = (int)x0f, y0 = (int)y0f;
    bool vx0 = (unsigned)x0 < 96u, vx1 = (unsigned)(x0 + 1) < 96u;
    bool vy0 = (unsigned)y0 < 96u, vy1 = (unsigned)(y0 + 1) < 96u;
    float w00 = (1.f - wy) * (1.f - wx), w01 = (1.f - wy) * wx;
    float w10 = wy * (1.f - wx),         w11 = wy * wx;
    int o00 = y0 * 96 + x0;
    float v = 0.f;
    if (p0) {
      float a00 = (vy0 && vx0) ? p0[o00]      : 0.f;
      float a01 = (vy0 && vx1) ? p0[o00 + 1]  : 0.f;
      float a10 = (vy1 && vx0) ? p0[o00 + 96] : 0.f;
      float a11 = (vy1 && vx1) ? p0[o00 + 97] : 0.f;
      v += wpl0 * (w00*a00 + w01*a01 + w10*a10 + w11*a11);
    }
    if (p1) {
      float a00 = (vy0 && vx0) ? p1[o00]      : 0.f;
      float a01 = (vy0 && vx1) ? p1[o00 + 1]  : 0.f;
      float a10 = (vy1 && vx0) ? p1[o00 + 96] : 0.f;
      float a11 = (vy1 && vx1) ? p1[o00 + 97] : 0.f;
      v += wpl1 * (w00*a00 + w01*a01 + w10*a10 + w11*a11);
    }
    dst[k * 256] = v;
    sum += v;
    sumsq += v * v;
    // advance (w,h) by 256 pixels: w += 64 (mod 96), h += 2 (+carry)
    int wn = w + 64;
    int carry = (wn >= 96) ? 1 : 0;
    w = wn - (carry ? 96 : 0);
    h += 2 + carry;
  }

  for (int off = 32; off > 0; off >>= 1) {
    sum   += __shfl_down(sum, off, 64);
    sumsq += __shfl_down(sumsq, off, 64);
  }
  __shared__ float rs[4], rq[4];
  int lane = t & 63, wvi = t >> 6;
  if (lane == 0) { rs[wvi] = sum; rq[wvi] = sumsq; }
  __syncthreads();
  if (t == 0) {
    part[bid * 2]     = rs[0] + rs[1] + rs[2] + rs[3];
    part[bid * 2 + 1] = rq[0] + rq[1] + rq[2] + rq[3];
  }
}

// ---------------------------------------------------------------------------
// Kernel 3b (R5): combine quarter partials -> nrm1 scale/bias.
// ---------------------------------------------------------------------------
__global__ __launch_bounds__(256) void finalize_nrm_kernel(
    const float* __restrict__ part, const float* __restrict__ gb,
    float* __restrict__ nrm)
{
  int bc = blockIdx.x * 256 + threadIdx.x;   // 4 blocks x 256
  float S = 0.f, Q = 0.f;
  #pragma unroll
  for (int q = 0; q < 4; q++) {
    S += part[(bc * 4 + q) * 2];
    Q += part[(bc * 4 + q) * 2 + 1];
  }
  float m = S * (1.f / 9216.f);
  float var = Q * (1.f / 9216.f) - m * m;
  float rstd = rsqrtf(var + 1e-5f);
  float sc = (1.f + gb[bc*2]) * rstd;
  nrm[bc*2] = sc;
  nrm[bc*2 + 1] = gb[bc*2 + 1] - m * sc;
}

// ---------------------------------------------------------------------------
// Kernel 4: per-plane stats of conv1 output (for AdaIN-2) — unchanged.
// ---------------------------------------------------------------------------
__global__ __launch_bounds__(256) void stats_kernel(
    const float* __restrict__ x, const float* __restrict__ gb,
    float* __restrict__ nrm)
{
  int bc = blockIdx.x;
  const float4* p = (const float4*)(x + (size_t)bc * HWN);
  float sum = 0.f, sumsq = 0.f;
  for (int i = threadIdx.x; i < HWN / 4; i += 256) {
    float4 v = p[i];
    sum   += v.x + v.y + v.z + v.w;
    sumsq += v.x*v.x + v.y*v.y + v.z*v.z + v.w*v.w;
  }
  for (int off = 32; off > 0; off >>= 1) {
    sum   += __shfl_down(sum, off, 64);
    sumsq += __shfl_down(sumsq, off, 64);
  }
  __shared__ float rs[4], rq[4];
  int lane = threadIdx.x & 63, wv = threadIdx.x >> 6;
  if (lane == 0) { rs[wv] = sum; rq[wv] = sumsq; }
  __syncthreads();
  if (threadIdx.x == 0) {
    float S = rs[0] + rs[1] + rs[2] + rs[3];
    float Q = rq[0] + rq[1] + rq[2] + rq[3];
    float m = S * (1.f / 9216.f);
    float var = Q * (1.f / 9216.f) - m * m;
    float rstd = rsqrtf(var + 1e-5f);
    float sc = (1.f + gb[bc*2]) * rstd;
    nrm[bc*2] = sc;
    nrm[bc*2 + 1] = gb[bc*2 + 1] - m * sc;
  }
}

// ---------------------------------------------------------------------------
// Kernel 5: transpose + fused AdaIN(scale/bias) + lrelu + bf16 cvt (unchanged).
// ---------------------------------------------------------------------------
__global__ __launch_bounds__(256) void transpose_norm_kernel(
    const float* __restrict__ x, const float* __restrict__ nrm,
    unsigned short* __restrict__ xt)
{
  int hi = blockIdx.x;
  int b  = blockIdx.y;
  unsigned short* dst = xt + (size_t)b * XT_PLANE + (size_t)hi * (XT_W * CH);
  int t = threadIdx.x;
  int h = hi - 1;
  u16x8 zero = {0,0,0,0,0,0,0,0};
  if (h < 0 || h >= 96) {
    for (int c = t; c < XT_W * CH / 8; c += 256) ((u16x8*)dst)[c] = zero;
    return;
  }
  __shared__ unsigned short s[96 * 256];  // [w][ci]
  int ci = t;
  float sc = nrm[(b*256 + ci)*2], bi = nrm[(b*256 + ci)*2 + 1];
  const float* src = x + ((size_t)(b*256 + ci)) * HWN + h * 96;
  for (int wg = 0; wg < 24; wg++) {
    float4 v = *(const float4*)(src + wg * 4);
    float y0 = fmaf(v.x, sc, bi); y0 = (y0 >= 0.f) ? y0 : 0.2f * y0;
    float y1 = fmaf(v.y, sc, bi); y1 = (y1 >= 0.f) ? y1 : 0.2f * y1;
    float y2 = fmaf(v.z, sc, bi); y2 = (y2 >= 0.f) ? y2 : 0.2f * y2;
    float y3 = fmaf(v.w, sc, bi); y3 = (y3 >= 0.f) ? y3 : 0.2f * y3;
    s[(wg*4 + 0) * 256 + ci] = f2bf(y0);
    s[(wg*4 + 1) * 256 + ci] = f2bf(y1);
    s[(wg*4 + 2) * 256 + ci] = f2bf(y2);
    s[(wg*4 + 3) * 256 + ci] = f2bf(y3);
  }
  __syncthreads();
  for (int c = t; c < 98 * 32; c += 256) {
    int w = c >> 5, p = c & 31;
    u16x8 v = zero;
    if (w >= 1 && w <= 96) v = *(const u16x8*)&s[(w - 1) * 256 + p * 8];
    ((u16x8*)dst)[c] = v;
  }
}

// ---------------------------------------------------------------------------
// Kernel 6: 3x3 conv 256->256, bf16 MFMA implicit GEMM (unchanged from R4).
// ---------------------------------------------------------------------------
__global__ __launch_bounds__(128) void conv_mfma_kernel(
    const unsigned short* __restrict__ xt,   // [4][98][98][256] bf16
    const unsigned short* __restrict__ wf,   // frag layout (see prep)
    const float* __restrict__ cb,
    float* __restrict__ out)                 // [4][256][96][96] f32
{
  __shared__ __align__(16) unsigned short s_in[2][6272]; // [buf][r4*half2*w98*8ci]

  int hb = blockIdx.x, coblk = blockIdx.y, b = blockIdx.z;
  int co0 = coblk * 64, h0 = hb * 2;
  int t = threadIdx.x, lane = t & 63, wv = t >> 6;
  int l31 = lane & 31, lhi = lane >> 5;
  const unsigned short* xtb = xt + (size_t)b * XT_PLANE;

  int pre_g[7], pre_l[7];
  #pragma unroll
  for (int i = 0; i < 7; i++) {
    int c = t + i * 128;
    if (c < 784) {
      int r = c / 196;
      int rem = c - r * 196;
      int half = rem / 98;
      int w = rem - half * 98;
      pre_g[i] = ((h0 + r) * 98 + w) * 256 + half * 8;
      pre_l[i] = c * 8;
    }
  }

  f32x16 acc[2][3];
  #pragma unroll
  for (int m = 0; m < 2; m++)
    #pragma unroll
    for (int n = 0; n < 3; n++)
      #pragma unroll
      for (int i = 0; i < 16; i++) acc[m][n][i] = 0.f;

  const unsigned short* wfb = wf + (size_t)(coblk * 16) * 9216 + lane * 8;

  u16x8 stg[7];
  #pragma unroll
  for (int i = 0; i < 6; i++) stg[i] = *(const u16x8*)(xtb + pre_g[i]);
  if (t < 16) stg[6] = *(const u16x8*)(xtb + pre_g[6]);
  #pragma unroll
  for (int i = 0; i < 6; i++) *(u16x8*)(&s_in[0][pre_l[i]]) = stg[i];
  if (t < 16) *(u16x8*)(&s_in[0][pre_l[6]]) = stg[6];
  __syncthreads();

  int buf = 0;
  int boff = (lhi * 98 + l31) * 8;
  #pragma unroll 1
  for (int ks = 0; ks < 16; ks++) {
    const unsigned short* wk = wfb + (size_t)ks * 9216;
    bfrag wa[9][2];
    #pragma unroll
    for (int tap = 0; tap < 9; tap++) {
      wa[tap][0] = *(const bfrag*)(wk + tap * 1024);
      wa[tap][1] = *(const bfrag*)(wk + tap * 1024 + 512);
    }
    if (ks < 15) {
      int cib = (ks + 1) * 16;
      #pragma unroll
      for (int i = 0; i < 6; i++) stg[i] = *(const u16x8*)(xtb + pre_g[i] + cib);
      if (t < 16) stg[6] = *(const u16x8*)(xtb + pre_g[6] + cib);
    }
    const unsigned short* sb = s_in[buf];
    #pragma unroll
    for (int ky = 0; ky < 3; ky++) {
      const unsigned short* srow = sb + (wv + ky) * (2 * 98 * 8);
      #pragma unroll
      for (int kx = 0; kx < 3; kx++) {
        int tap = ky * 3 + kx;
        #pragma unroll
        for (int n = 0; n < 3; n++) {
          bfrag bv = *(const bfrag*)(srow + (n * 32 + kx) * 8 + boff);
          acc[0][n] = __builtin_amdgcn_mfma_f32_32x32x16_bf16(wa[tap][0], bv, acc[0][n], 0, 0, 0);
          acc[1][n] = __builtin_amdgcn_mfma_f32_32x32x16_bf16(wa[tap][1], bv, acc[1][n], 0, 0, 0);
        }
      }
    }
    if (ks < 15) {
      unsigned short* sn = s_in[buf ^ 1];
      #pragma unroll
      for (int i = 0; i < 6; i++) *(u16x8*)(&sn[pre_l[i]]) = stg[i];
      if (t < 16) *(u16x8*)(&sn[pre_l[6]]) = stg[6];
    }
    __syncthreads();
    buf ^= 1;
  }

  int h = h0 + wv;
  #pragma unroll
  for (int m = 0; m < 2; m++) {
    #pragma unroll
    for (int r = 0; r < 16; r++) {
      int row = (r & 3) + 8 * (r >> 2) + 4 * lhi;
      int co = co0 + m * 32 + row;
      float bv = cb[co];
      size_t base = ((size_t)(b * 256 + co) * 96 + h) * 96;
      #pragma unroll
      for (int n = 0; n < 3; n++) {
        out[base + n * 32 + l31] = acc[m][n][r] + bv;
      }
    }
  }
}

// ---------------------------------------------------------------------------
extern "C" void kernel_launch(void* const* d_in, const int* in_sizes, int n_in,
                              void* d_out, int out_size, void* d_ws, size_t ws_size,
                              hipStream_t stream)
{
  const float* fm    = (const float*)d_in[0];
  const float* para  = (const float*)d_in[1];
  const float* style = (const float*)d_in[2];
  const float* cw  = (const float*)d_in[3];
  const float* cb  = (const float*)d_in[4];
  const float* sw  = (const float*)d_in[5];
  const float* sb  = (const float*)d_in[6];
  const float* rw  = (const float*)d_in[7];
  const float* rb  = (const float*)d_in[8];
  const float* tw  = (const float*)d_in[9];
  const float* tb  = (const float*)d_in[10];
  const float* a1w = (const float*)d_in[11];
  const float* a1b = (const float*)d_in[12];
  const float* g1w = (const float*)d_in[13];
  const float* g1b = (const float*)d_in[14];
  const float* b1w = (const float*)d_in[15];
  const float* b1b = (const float*)d_in[16];
  const float* c1w = (const float*)d_in[17];
  const float* c1b = (const float*)d_in[18];
  const float* a2w = (const float*)d_in[19];
  const float* a2b = (const float*)d_in[20];
  const float* g2w = (const float*)d_in[21];
  const float* g2b = (const float*)d_in[22];
  const float* b2w = (const float*)d_in[23];
  const float* b2b = (const float*)d_in[24];
  const float* c2w = (const float*)d_in[25];
  const float* c2b = (const float*)d_in[26];

  float* outf = (float*)d_out;

  unsigned short* xtbuf = (unsigned short*)d_ws;                 // 4*98*98*256 bf16
  unsigned short* wf1   = xtbuf + (size_t)BATCH * XT_PLANE;      // 589824
  unsigned short* wf2   = wf1 + 9 * 256 * 256;
  float* fws  = (float*)(wf2 + 9 * 256 * 256);
  float* warp = fws;                   // 4096
  float* gb1  = warp + 4 * 1024;       // 2048
  float* gb2  = gb1 + 2 * 1024;        // 2048
  float* nrm1 = gb2 + 2 * 1024;        // 2048
  float* nrm2 = nrm1 + 2 * 1024;       // 2048
  float* part = nrm2 + 2 * 1024;       // 4096*2 floats

  params_kernel<<<4, 256, 0, stream>>>(para, style, cw, cb, sw, sb, rw, rb, tw, tb,
      a1w, a1b, g1w, g1b, b1w, b1b, a2w, a2b, g2w, g2b, b2w, b2b, warp, gb1, gb2);
  prep_weights_kernel<<<512, 256, 0, stream>>>(c1w, c2w, wf1, wf2);
  adaat_kernel<<<4096, 256, 0, stream>>>(fm, warp, outf, part);
  finalize_nrm_kernel<<<4, 256, 0, stream>>>(part, gb1, nrm1);
  transpose_norm_kernel<<<dim3(98, 4), 256, 0, stream>>>(outf, nrm1, xtbuf);
  conv_mfma_kernel<<<dim3(48, 4, 4), 128, 0, stream>>>(xtbuf, wf1, c1b, outf);
  stats_kernel<<<1024, 256, 0, stream>>>(outf, gb2, nrm2);
  transpose_norm_kernel<<<dim3(98, 4), 256, 0, stream>>>(outf, nrm2, xtbuf);
  conv_mfma_kernel<<<dim3(48, 4, 4), 128, 0, stream>>>(xtbuf, wf2, c2b, outf);
}